// Round 19
// baseline (697.751 us; speedup 1.0000x reference)
//
#include <hip/hip_runtime.h>
#include <hip/hip_bf16.h>

typedef __hip_bfloat16 bf16;
typedef __attribute__((ext_vector_type(8))) short bh8;   // 8 bf16 (MFMA A/B frag)
typedef __attribute__((ext_vector_type(4))) short bh4;   // 4 bf16 (8B pack)
typedef __attribute__((ext_vector_type(4))) float f4;    // MFMA C/D frag

#define TOKENS 200704   // 16*112*112 = 4096 windows * 49
#define CDIM   192

__device__ __forceinline__ void gload16(const bf16* g, bf16* l) {
    __builtin_amdgcn_global_load_lds((const __attribute__((address_space(1))) void*)g,
                                     (__attribute__((address_space(3))) void*)l,
                                     16, 0, 0);
}
#define MFMA __builtin_amdgcn_mfma_f32_16x16x32_bf16

__device__ __forceinline__ short f2bs(float v) {
    bf16 h = __float2bfloat16(v); return *(short*)&h;
}

// window-row -> token index ((b,hs,ws) shifted back by +3)
__device__ __forceinline__ int row2tok(int row) {
    int win = row / 49, n = row - win * 49;
    int b = win >> 8, rem = win & 255;
    int hs = (rem >> 4) * 7 + n / 7;
    int wsx = (rem & 15) * 7 + n % 7;
    int hh = hs + 3; if (hh >= 112) hh -= 112;
    int ww = wsx + 3; if (ww >= 112) ww -= 112;
    return (b * 112 + hh) * 112 + ww;
}

// ---- fp32 -> bf16 conversion of all four weight matrices (contiguous dst) ----
__global__ void cvt_all(const float* __restrict__ a, const float* __restrict__ b,
                        const float* __restrict__ c, const float* __restrict__ d,
                        bf16* __restrict__ dst) {
    int i = blockIdx.x * 256 + threadIdx.x;
    if (i >= 442368) return;
    float v;
    if (i < 110592)       v = a[i];
    else if (i < 147456)  v = b[i - 110592];
    else if (i < 294912)  v = c[i - 147456];
    else                  v = d[i - 294912];
    dst[i] = __float2bfloat16(v);
}

// ---- padded bias+mask: bmp[cls][h][q:64][k:64]; k>=49 -> -1e30 (masks GEMM padding) ----
__global__ void bmp_kernel(const int* __restrict__ rpi, const float* __restrict__ tab,
                           const float* __restrict__ mask, float* __restrict__ bmp) {
    int idx = blockIdx.x * 256 + threadIdx.x;
    if (idx >= 98304) return;
    int cls = idx / 24576, rem = idx - cls * 24576;
    int h = rem >> 12, qk = rem & 4095;
    int qq = qk >> 6, kk = qk & 63;
    float v;
    if (kk >= 49) v = -1e30f;
    else if (qq >= 49) v = 0.f;
    else {
        int rep = ((cls & 2) ? 240 : 0) + ((cls & 1) ? 15 : 0);
        v = tab[rpi[qq * 49 + kk] * 6 + h] + mask[rep * 2401 + qq * 49 + kk];
    }
    bmp[idx] = v;
}

// ---- LayerNorm1 (fp32 in, bf16 out), shift(-3,-3) + window partition gather ----
__global__ __launch_bounds__(256)
void ln_kernel(const float* __restrict__ src, const float* __restrict__ gw,
               const float* __restrict__ bw, bf16* __restrict__ dst) {
    const int lane = threadIdx.x & 63;
    const int gwv  = (blockIdx.x * 256 + threadIdx.x) >> 6;
    const int nwv  = (gridDim.x * 256) >> 6;
    const float g0 = gw[lane], g1 = gw[lane + 64], g2 = gw[lane + 128];
    const float b0 = bw[lane], b1 = bw[lane + 64], b2 = bw[lane + 128];
    for (int row = gwv; row < TOKENS; row += nwv) {
        const float* p = src + (size_t)row2tok(row) * CDIM;
        float v0 = p[lane], v1 = p[lane + 64], v2 = p[lane + 128];
        float s = v0 + v1 + v2;
        float q = v0 * v0 + v1 * v1 + v2 * v2;
        #pragma unroll
        for (int o = 32; o; o >>= 1) { s += __shfl_xor(s, o, 64); q += __shfl_xor(q, o, 64); }
        float mean = s * (1.f / 192.f);
        float var  = q * (1.f / 192.f) - mean * mean;
        float rstd = rsqrtf(var + 1e-5f);
        bf16* d = dst + (size_t)row * CDIM;
        d[lane]       = __float2bfloat16((v0 - mean) * rstd * g0 + b0);
        d[lane + 64]  = __float2bfloat16((v1 - mean) * rstd * g1 + b1);
        d[lane + 128] = __float2bfloat16((v2 - mean) * rstd * g2 + b2);
    }
}

// ==== fused qkv-GEMM + MFMA attention (r13): 1 window/block, 6 waves (wave=head) ====
__global__ __launch_bounds__(384, 2)
void qkvattn_kernel(const bf16* __restrict__ xw, const bf16* __restrict__ wq,
                    const float* __restrict__ qkvb, const float* __restrict__ bmp,
                    bf16* __restrict__ attno) {
    __shared__ __align__(16) bf16 xsf[6][64][32];       // 24 KiB x-tile; later vt[6][32][64]
    __shared__ __align__(16) bf16 qk[6][2][64][32];     // 48 KiB Q,K; reused as P[h][64][64]
    const int tid = threadIdx.x, h = tid >> 6, lane = tid & 63;
    const int r = lane & 15, q = lane >> 4;
    const int win = blockIdx.x;
    const int sxk = (q ^ ((r >> 1) & 3)) << 3;

    #pragma unroll
    for (int it = 0; it < 4; ++it) {
        int l = it * 384 + tid;
        int ks = l >> 8, rem = l & 255, tok = rem >> 2;
        int kg = (rem & 3) ^ ((tok >> 1) & 3);
        int srow = win * 49 + tok; if (srow > 200703) srow = 200703;
        gload16(xw + (size_t)srow * 192 + ks * 32 + kg * 8,
                &xsf[0][0][0] + (size_t)l * 8);
    }
    const bf16* wqh = wq + (size_t)(h * 32 + r) * 192 + q * 8;
    bh8 wqk[4], wv[2];
    #pragma unroll
    for (int i = 0; i < 4; ++i)
        wqk[i] = *(const bh8*)(wqh + (size_t)((i >> 1) * 192 + (i & 1) * 16) * 192);
    #pragma unroll
    for (int jv = 0; jv < 2; ++jv)
        wv[jv] = *(const bh8*)(wqh + (size_t)(384 + jv * 16) * 192);
    __syncthreads();
    f4 aqk[4][4] = {}, av[4][2] = {};
    #pragma unroll
    for (int ks = 0; ks < 6; ++ks) {
        bh8 nqk[4], nv[2];
        if (ks < 5) {
            #pragma unroll
            for (int i = 0; i < 4; ++i)
                nqk[i] = *(const bh8*)(wqh + (size_t)((i >> 1) * 192 + (i & 1) * 16) * 192 + (ks + 1) * 32);
            #pragma unroll
            for (int jv = 0; jv < 2; ++jv)
                nv[jv] = *(const bh8*)(wqh + (size_t)(384 + jv * 16) * 192 + (ks + 1) * 32);
        }
        bh8 xf[4];
        #pragma unroll
        for (int mt = 0; mt < 4; ++mt)
            xf[mt] = *(const bh8*)&xsf[ks][mt * 16 + r][sxk];
        #pragma unroll
        for (int i = 0; i < 4; ++i)
            #pragma unroll
            for (int jn = 0; jn < 4; ++jn)
                aqk[i][jn] = MFMA(wqk[i], xf[jn], aqk[i][jn], 0, 0, 0);  // m=qkcol,n=token
        #pragma unroll
        for (int mt = 0; mt < 4; ++mt)
            #pragma unroll
            for (int jv = 0; jv < 2; ++jv)
                av[mt][jv] = MFMA(xf[mt], wv[jv], av[mt][jv], 0, 0, 0);  // m=token,n=vd
        if (ks < 5) {
            #pragma unroll
            for (int i = 0; i < 4; ++i) wqk[i] = nqk[i];
            wv[0] = nv[0]; wv[1] = nv[1];
        }
    }
    __syncthreads();   // xsf dead for ALL waves; vt overlay is now safe
    bf16* qkh = &qk[h][0][0][0];           // Q plane [0..2048), K plane [2048..4096)
    #pragma unroll
    for (int i = 0; i < 4; ++i) {
        const int t = i >> 1;
        const f4 bz = *(const f4*)&qkvb[t * 192 + h * 32 + (i & 1) * 16 + q * 4];
        const float sc = (i < 2) ? 0.17677669529663689f : 1.0f;  // scale Q only
        #pragma unroll
        for (int jn = 0; jn < 4; ++jn) {
            const int tok = jn * 16 + r;
            bh4 w;
            #pragma unroll
            for (int rr = 0; rr < 4; ++rr)
                w[rr] = f2bs((aqk[i][jn][rr] + bz[rr]) * sc);
            const int g = (((i & 1) * 4 + q) ^ ((tok & 3) << 1));
            *(bh4*)&qkh[(t * 64 + tok) * 32 + g * 4] = w;
        }
    }
    bf16* vth = &xsf[0][0][0] + h * 2048;  // vt overlay [32 d][64 tok] per head
    #pragma unroll
    for (int jv = 0; jv < 2; ++jv) {
        const float bv = qkvb[384 + h * 32 + jv * 16 + r];
        const int d = jv * 16 + r;
        #pragma unroll
        for (int mt = 0; mt < 4; ++mt) {
            bh4 w;
            #pragma unroll
            for (int rr = 0; rr < 4; ++rr)
                w[rr] = f2bs(av[mt][jv][rr] + bv);
            const int g = ((mt * 4 + q) ^ ((r & 7) << 1));
            *(bh4*)&vth[d * 64 + g * 4] = w;
        }
    }
    f4 as[4][4] = {};
    {
        const int sl = ((2 * q) ^ ((r & 3) << 1)) << 2;
        bh8 kf[4], qf[4];
        #pragma unroll
        for (int mt = 0; mt < 4; ++mt)
            kf[mt] = *(const bh8*)&qkh[(64 + mt * 16 + r) * 32 + sl];
        #pragma unroll
        for (int jn = 0; jn < 4; ++jn)
            qf[jn] = *(const bh8*)&qkh[(jn * 16 + r) * 32 + sl];
        #pragma unroll
        for (int mt = 0; mt < 4; ++mt)
            #pragma unroll
            for (int jn = 0; jn < 4; ++jn)
                as[mt][jn] = MFMA(kf[mt], qf[jn], as[mt][jn], 0, 0, 0);
    }
    const int rem = win & 255;
    const int cls = (((rem >> 4) == 15) ? 2 : 0) + (((rem & 15) == 15) ? 1 : 0);
    const float* bmh = bmp + ((size_t)(cls * 6 + h) << 12);
    #pragma unroll
    for (int jn = 0; jn < 4; ++jn) {
        const int qq = jn * 16 + r;
        #pragma unroll
        for (int mt = 0; mt < 4; ++mt) {
            const f4 b = *(const f4*)&bmh[qq * 64 + mt * 16 + q * 4];
            #pragma unroll
            for (int rr = 0; rr < 4; ++rr) as[mt][jn][rr] += b[rr];
        }
    }
    float inv4[4];
    #pragma unroll
    for (int jn = 0; jn < 4; ++jn) {
        float mx = -1e30f;
        #pragma unroll
        for (int mt = 0; mt < 4; ++mt)
            #pragma unroll
            for (int rr = 0; rr < 4; ++rr) mx = fmaxf(mx, as[mt][jn][rr]);
        mx = fmaxf(mx, __shfl_xor(mx, 16, 64));
        mx = fmaxf(mx, __shfl_xor(mx, 32, 64));
        float sm = 0.f;
        #pragma unroll
        for (int mt = 0; mt < 4; ++mt)
            #pragma unroll
            for (int rr = 0; rr < 4; ++rr) {
                float e = __expf(as[mt][jn][rr] - mx);
                as[mt][jn][rr] = e; sm += e;
            }
        sm += __shfl_xor(sm, 16, 64);
        sm += __shfl_xor(sm, 32, 64);
        inv4[jn] = __builtin_amdgcn_rcpf(sm);   // sm >= 1
    }
    #pragma unroll
    for (int jn = 0; jn < 4; ++jn) {
        const int qq = jn * 16 + r;
        #pragma unroll
        for (int mt = 0; mt < 4; ++mt) {
            bh4 w;
            #pragma unroll
            for (int rr = 0; rr < 4; ++rr) w[rr] = f2bs(as[mt][jn][rr] * inv4[jn]);
            const int g = ((mt * 4 + q) ^ ((r & 7) << 1));
            *(bh4*)&qkh[qq * 64 + g * 4] = w;
        }
    }
    f4 ao[4][2] = {};
    #pragma unroll
    for (int k2 = 0; k2 < 2; ++k2) {
        const int sl = ((k2 * 8 + 2 * q) ^ ((r & 7) << 1)) << 2;
        bh8 pf[4], vf[2];
        #pragma unroll
        for (int mt = 0; mt < 4; ++mt)
            pf[mt] = *(const bh8*)&qkh[(mt * 16 + r) * 64 + sl];
        #pragma unroll
        for (int jv = 0; jv < 2; ++jv)
            vf[jv] = *(const bh8*)&vth[(jv * 16 + r) * 64 + sl];
        #pragma unroll
        for (int mt = 0; mt < 4; ++mt)
            #pragma unroll
            for (int jv = 0; jv < 2; ++jv)
                ao[mt][jv] = MFMA(pf[mt], vf[jv], ao[mt][jv], 0, 0, 0);
    }
    #pragma unroll
    for (int mt = 0; mt < 4; ++mt)
        #pragma unroll
        for (int jv = 0; jv < 2; ++jv) {
            const int d = jv * 16 + r;
            #pragma unroll
            for (int rr = 0; rr < 4; ++rr) {
                const int qq = mt * 16 + q * 4 + rr;
                if (qq < 49)
                    attno[((size_t)win * 49 + qq) * 192 + h * 32 + d] =
                        __float2bfloat16(ao[mt][jv][rr]);
            }
        }
}

// ==== fused proj + residual + LN2 + MLP: 128 window-rows/block, 8 waves (2x4) ====
// LDS exactly 80 KiB (As 48K + Hs 32K; LN stats alias Hs[0]) -> 2 blocks/CU
// = 16 waves/CU.  Per-wave shapes identical to the 4-wave version (VGPR ~84).
__global__ __launch_bounds__(512, 2)
void projmlp_kernel(const bf16* __restrict__ attno, const bf16* __restrict__ wp,
                    const float* __restrict__ projb, const float* __restrict__ xres,
                    const float* __restrict__ g2, const float* __restrict__ b2g,
                    const bf16* __restrict__ w1, const float* __restrict__ b1,
                    const bf16* __restrict__ w2, const float* __restrict__ b2,
                    float* __restrict__ out) {
    __shared__ __align__(16) bf16 As[6][128][32];   // 48 KiB: attno tile -> LN2 out
    __shared__ __align__(16) bf16 Hs[2][128][64];   // 32 KiB ping-pong; [0] aliases stats
    float* rsum = (float*)&Hs[0][0][0];             // [128][4]
    float* rsq  = rsum + 512;                       // [128][4]
    float* mr   = rsum + 1024;                      // [128][2]
    const int tid = threadIdx.x, wid = tid >> 6, lane = tid & 63;
    const int wm = wid >> 2, wn = wid & 3;
    const int mbase = blockIdx.x * 128;
    const int r = lane & 15, q = lane >> 4, ko = q * 8;
    const int sxA = (q ^ ((r >> 1) & 3)) << 3;
    bf16* As0 = &As[0][0][0];
    // ---- stage attno tile: 3072 x 16B chunks (swizzled source, linear dest) ----
    #pragma unroll
    for (int it = 0; it < 6; ++it) {
        int l = it * 512 + tid;
        int ks = l >> 9, rem2 = l & 511, row = rem2 >> 2;
        int g = (rem2 & 3) ^ ((row >> 1) & 3);
        gload16(attno + (size_t)(mbase + row) * 192 + ks * 32 + g * 8,
                As0 + (size_t)l * 8);
    }
    __syncthreads();
    // ---- proj GEMM: wave (wm,wn) does rows [wm*64,+64) x cols [wn*48,+48), K=192 ----
    f4 pacc[4][3] = {};
    #pragma unroll
    for (int ks = 0; ks < 6; ++ks) {
        bh8 wpf[3];
        #pragma unroll
        for (int j = 0; j < 3; ++j)
            wpf[j] = *(const bh8*)&wp[(size_t)(wn * 48 + j * 16 + r) * 192 + ks * 32 + ko];
        #pragma unroll
        for (int i = 0; i < 4; ++i) {
            bh8 af = *(const bh8*)(As0 + ks * 4096 + (wm * 64 + i * 16 + r) * 32 + sxA);
            #pragma unroll
            for (int j = 0; j < 3; ++j)
                pacc[i][j] = MFMA(af, wpf[j], pacc[i][j], 0, 0, 0);
        }
    }
    // ---- epilogue: + projb + x residual; per-row LN2 stats ----
    float pbv[3];
    #pragma unroll
    for (int j = 0; j < 3; ++j) pbv[j] = projb[wn * 48 + j * 16 + r];
    #pragma unroll
    for (int i = 0; i < 4; ++i) {
        int tok[4];
        float ps[4] = {}, pq2[4] = {};
        #pragma unroll
        for (int rr = 0; rr < 4; ++rr)
            tok[rr] = row2tok(mbase + wm * 64 + i * 16 + q * 4 + rr);
        #pragma unroll
        for (int j = 0; j < 3; ++j) {
            const int col = wn * 48 + j * 16 + r;
            #pragma unroll
            for (int rr = 0; rr < 4; ++rr) {
                float v = pacc[i][j][rr] + pbv[j] + xres[(size_t)tok[rr] * 192 + col];
                pacc[i][j][rr] = v;
                ps[rr] += v; pq2[rr] += v * v;
            }
        }
        #pragma unroll
        for (int rr = 0; rr < 4; ++rr) {
            float s = ps[rr], qq = pq2[rr];
            #pragma unroll
            for (int o = 1; o < 16; o <<= 1) { s += __shfl_xor(s, o, 64); qq += __shfl_xor(qq, o, 64); }
            if (r == 0) {
                const int row = wm * 64 + i * 16 + q * 4 + rr;
                rsum[row * 4 + wn] = s; rsq[row * 4 + wn] = qq;
            }
        }
    }
    __syncthreads();   // As reads done (proj GEMM) + rsum/rsq visible
    if (tid < 128) {
        float s = 0.f, qq = 0.f;
        #pragma unroll
        for (int w = 0; w < 4; ++w) { s += rsum[tid * 4 + w]; qq += rsq[tid * 4 + w]; }
        float m = s * (1.f / 192.f);
        float var = qq * (1.f / 192.f) - m * m;
        mr[tid * 2] = m; mr[tid * 2 + 1] = rsqrtf(var + 1e-5f);
    }
    __syncthreads();
    // ---- write hn = LN2(x1) into dead As (inverse-swizzled slots) ----
    #pragma unroll
    for (int j = 0; j < 3; ++j) {
        const int col = wn * 48 + j * 16 + r;
        const float gv = g2[col], bvv = b2g[col];
        const int ks2 = col >> 5, w32 = col & 31;
        #pragma unroll
        for (int i = 0; i < 4; ++i)
            #pragma unroll
            for (int rr = 0; rr < 4; ++rr) {
                const int row = wm * 64 + i * 16 + q * 4 + rr;
                float hv = (pacc[i][j][rr] - mr[row * 2]) * mr[row * 2 + 1] * gv + bvv;
                const int slot8 = (w32 >> 3) ^ ((row >> 1) & 3);
                As0[ks2 * 4096 + row * 32 + slot8 * 8 + (w32 & 7)] = __float2bfloat16(hv);
            }
    }
    __syncthreads();   // mr reads done; Hs[0] free for mlp chunk 0
    // ---- mlp chunk loop (r6 structure + rcp-GELU) ----
    f4 acc2[4][3] = {};
    for (int c = 0; c < 12; ++c) {
        const int cb = c * 64;
        bh8 w1f[6];
        #pragma unroll
        for (int ks = 0; ks < 6; ++ks)
            w1f[ks] = *(const bh8*)&w1[(size_t)(cb + wn * 16 + r) * 192 + ks * 32 + ko];
        f4 acc1[4] = {};
        #pragma unroll
        for (int ks = 0; ks < 6; ++ks)
            #pragma unroll
            for (int i = 0; i < 4; ++i) {
                bh8 af = *(const bh8*)(As0 + ks * 4096 + (wm * 64 + i * 16 + r) * 32 + sxA);
                acc1[i] = MFMA(af, w1f[ks], acc1[i], 0, 0, 0);
            }
        bh8 w2f[2][3];
        #pragma unroll
        for (int k2 = 0; k2 < 2; ++k2)
            #pragma unroll
            for (int j = 0; j < 3; ++j)
                w2f[k2][j] = *(const bh8*)&w2[(size_t)(wn * 48 + j * 16 + r) * 768 + cb + k2 * 32 + ko];
        const float b1v = b1[cb + wn * 16 + r];
        bf16 (*Hp)[64] = Hs[c & 1];
        #pragma unroll
        for (int i = 0; i < 4; ++i) {
            #pragma unroll
            for (int rr = 0; rr < 4; ++rr) {
                int row = wm * 64 + i * 16 + q * 4 + rr;
                int col = wn * 16 + r;
                float v = acc1[i][rr] + b1v;
                float u = v * (1.5957691216f + 0.0713548162f * v * v);
                float en = __expf(-u);                        // overflow-safe sigmoid form
                float t = __builtin_amdgcn_rcpf(1.f + en);
                Hp[row][(((col >> 3) ^ (row & 7)) << 3) | (col & 7)] =
                    __float2bfloat16(v * t);                  // gelu_tanh
            }
        }
        __syncthreads();
        #pragma unroll
        for (int k2 = 0; k2 < 2; ++k2)
            #pragma unroll
            for (int i = 0; i < 4; ++i) {
                int row = wm * 64 + i * 16 + r;
                bh8 af = *(const bh8*)(&Hp[row][0] + ((((k2 * 4 + q) ^ (row & 7)) & 7) << 3));
                #pragma unroll
                for (int j = 0; j < 3; ++j)
                    acc2[i][j] = MFMA(af, w2f[k2][j], acc2[i][j], 0, 0, 0);
            }
    }
    // ---- final: out = x1(regs) + mlp + b2 ; pure coalesced write, token scatter ----
    #pragma unroll
    for (int i = 0; i < 4; ++i) {
        int tok[4];
        #pragma unroll
        for (int rr = 0; rr < 4; ++rr)
            tok[rr] = row2tok(mbase + wm * 64 + i * 16 + q * 4 + rr);
        #pragma unroll
        for (int j = 0; j < 3; ++j) {
            int ncol = wn * 48 + j * 16 + r;
            float bv = b2[ncol];
            #pragma unroll
            for (int rr = 0; rr < 4; ++rr)
                out[(size_t)tok[rr] * 192 + ncol] = pacc[i][j][rr] + acc2[i][j][rr] + bv;
        }
    }
}

extern "C" void kernel_launch(void* const* d_in, const int* in_sizes, int n_in,
                              void* d_out, int out_size, void* d_ws, size_t ws_size,
                              hipStream_t stream) {
    const float* x     = (const float*)d_in[0];
    const float* mask  = (const float*)d_in[1];
    const int*   rpi   = (const int*)d_in[2];
    const float* rpb   = (const float*)d_in[3];
    const float* n1g   = (const float*)d_in[4];
    const float* n1b   = (const float*)d_in[5];
    const float* qkvw  = (const float*)d_in[6];
    const float* qkvb  = (const float*)d_in[7];
    const float* projw = (const float*)d_in[8];
    const float* projb = (const float*)d_in[9];
    const float* n2g   = (const float*)d_in[10];
    const float* n2b   = (const float*)d_in[11];
    const float* fc1w  = (const float*)d_in[12];
    const float* fc1b  = (const float*)d_in[13];
    const float* fc2w  = (const float*)d_in[14];
    const float* fc2b  = (const float*)d_in[15];

    // ws layout:
    //  [0, 77,070,336)            attno bf16 (window order)
    //  [77,070,336, 77,463,552)   bmp fp32 (4x6x64x64)
    //  [77,463,552, 78,348,288)   bf16 weights contiguous (wq|wp|w1|w2)
    // xw (LN1 out) lives in d_out (overwritten by projmlp's final stores).
    char* ws = (char*)d_ws;
    bf16*  attno  = (bf16*)ws;
    float* bmp    = (float*)(ws + 77070336);
    bf16*  wq     = (bf16*)(ws + 77463552);
    bf16*  wp     = (bf16*)(ws + 77684736);
    bf16*  w1     = (bf16*)(ws + 77758464);
    bf16*  w2     = (bf16*)(ws + 78053376);
    bf16*  xw     = (bf16*)d_out;

    cvt_all<<<1728, 256, 0, stream>>>(qkvw, projw, fc1w, fc2w, wq);
    bmp_kernel<<<384, 256, 0, stream>>>(rpi, rpb, mask, bmp);

    ln_kernel<<<2048, 256, 0, stream>>>(x, n1g, n1b, xw);
    qkvattn_kernel<<<4096, 384, 0, stream>>>(xw, wq, qkvb, bmp, attno);
    projmlp_kernel<<<1568, 512, 0, stream>>>(attno, wp, projb, x, n2g, n2b,
                                             w1, fc1b, w2, fc2b, (float*)d_out);
}

// Round 20
// 596.259 us; speedup vs baseline: 1.1702x; 1.1702x over previous
//
#include <hip/hip_runtime.h>
#include <hip/hip_bf16.h>

typedef __hip_bfloat16 bf16;
typedef __attribute__((ext_vector_type(8))) short bh8;   // 8 bf16 (MFMA A/B frag)
typedef __attribute__((ext_vector_type(4))) short bh4;   // 4 bf16 (8B pack)
typedef __attribute__((ext_vector_type(4))) float f4;    // MFMA C/D frag

#define TOKENS 200704   // 16*112*112 = 4096 windows * 49
#define CDIM   192

__device__ __forceinline__ void gload16(const bf16* g, bf16* l) {
    __builtin_amdgcn_global_load_lds((const __attribute__((address_space(1))) void*)g,
                                     (__attribute__((address_space(3))) void*)l,
                                     16, 0, 0);
}
#define MFMA __builtin_amdgcn_mfma_f32_16x16x32_bf16

__device__ __forceinline__ short f2bs(float v) {
    bf16 h = __float2bfloat16(v); return *(short*)&h;
}

// window-row -> token index ((b,hs,ws) shifted back by +3)
__device__ __forceinline__ int row2tok(int row) {
    int win = row / 49, n = row - win * 49;
    int b = win >> 8, rem = win & 255;
    int hs = (rem >> 4) * 7 + n / 7;
    int wsx = (rem & 15) * 7 + n % 7;
    int hh = hs + 3; if (hh >= 112) hh -= 112;
    int ww = wsx + 3; if (ww >= 112) ww -= 112;
    return (b * 112 + hh) * 112 + ww;
}

// ---- fp32 -> bf16 conversion of all four weight matrices (contiguous dst) ----
__global__ void cvt_all(const float* __restrict__ a, const float* __restrict__ b,
                        const float* __restrict__ c, const float* __restrict__ d,
                        bf16* __restrict__ dst) {
    int i = blockIdx.x * 256 + threadIdx.x;
    if (i >= 442368) return;
    float v;
    if (i < 110592)       v = a[i];
    else if (i < 147456)  v = b[i - 110592];
    else if (i < 294912)  v = c[i - 147456];
    else                  v = d[i - 294912];
    dst[i] = __float2bfloat16(v);
}

// ---- padded bias+mask: bmp[cls][h][q:64][k:64]; k>=49 -> -1e30 (masks GEMM padding) ----
__global__ void bmp_kernel(const int* __restrict__ rpi, const float* __restrict__ tab,
                           const float* __restrict__ mask, float* __restrict__ bmp) {
    int idx = blockIdx.x * 256 + threadIdx.x;
    if (idx >= 98304) return;
    int cls = idx / 24576, rem = idx - cls * 24576;
    int h = rem >> 12, qk = rem & 4095;
    int qq = qk >> 6, kk = qk & 63;
    float v;
    if (kk >= 49) v = -1e30f;
    else if (qq >= 49) v = 0.f;
    else {
        int rep = ((cls & 2) ? 240 : 0) + ((cls & 1) ? 15 : 0);
        v = tab[rpi[qq * 49 + kk] * 6 + h] + mask[rep * 2401 + qq * 49 + kk];
    }
    bmp[idx] = v;
}

// ---- LayerNorm1 (fp32 in, bf16 out), shift(-3,-3) + window partition gather ----
__global__ __launch_bounds__(256)
void ln_kernel(const float* __restrict__ src, const float* __restrict__ gw,
               const float* __restrict__ bw, bf16* __restrict__ dst) {
    const int lane = threadIdx.x & 63;
    const int gwv  = (blockIdx.x * 256 + threadIdx.x) >> 6;
    const int nwv  = (gridDim.x * 256) >> 6;
    const float g0 = gw[lane], g1 = gw[lane + 64], g2 = gw[lane + 128];
    const float b0 = bw[lane], b1 = bw[lane + 64], b2 = bw[lane + 128];
    for (int row = gwv; row < TOKENS; row += nwv) {
        const float* p = src + (size_t)row2tok(row) * CDIM;
        float v0 = p[lane], v1 = p[lane + 64], v2 = p[lane + 128];
        float s = v0 + v1 + v2;
        float q = v0 * v0 + v1 * v1 + v2 * v2;
        #pragma unroll
        for (int o = 32; o; o >>= 1) { s += __shfl_xor(s, o, 64); q += __shfl_xor(q, o, 64); }
        float mean = s * (1.f / 192.f);
        float var  = q * (1.f / 192.f) - mean * mean;
        float rstd = rsqrtf(var + 1e-5f);
        bf16* d = dst + (size_t)row * CDIM;
        d[lane]       = __float2bfloat16((v0 - mean) * rstd * g0 + b0);
        d[lane + 64]  = __float2bfloat16((v1 - mean) * rstd * g1 + b1);
        d[lane + 128] = __float2bfloat16((v2 - mean) * rstd * g2 + b2);
    }
}

// ==== fused qkv-GEMM + MFMA attention (r13): 1 window/block, 6 waves (wave=head) ====
__global__ __launch_bounds__(384, 2)
void qkvattn_kernel(const bf16* __restrict__ xw, const bf16* __restrict__ wq,
                    const float* __restrict__ qkvb, const float* __restrict__ bmp,
                    bf16* __restrict__ attno) {
    __shared__ __align__(16) bf16 xsf[6][64][32];       // 24 KiB x-tile; later vt[6][32][64]
    __shared__ __align__(16) bf16 qk[6][2][64][32];     // 48 KiB Q,K; reused as P[h][64][64]
    const int tid = threadIdx.x, h = tid >> 6, lane = tid & 63;
    const int r = lane & 15, q = lane >> 4;
    const int win = blockIdx.x;
    const int sxk = (q ^ ((r >> 1) & 3)) << 3;

    #pragma unroll
    for (int it = 0; it < 4; ++it) {
        int l = it * 384 + tid;
        int ks = l >> 8, rem = l & 255, tok = rem >> 2;
        int kg = (rem & 3) ^ ((tok >> 1) & 3);
        int srow = win * 49 + tok; if (srow > 200703) srow = 200703;
        gload16(xw + (size_t)srow * 192 + ks * 32 + kg * 8,
                &xsf[0][0][0] + (size_t)l * 8);
    }
    const bf16* wqh = wq + (size_t)(h * 32 + r) * 192 + q * 8;
    bh8 wqk[4], wv[2];
    #pragma unroll
    for (int i = 0; i < 4; ++i)
        wqk[i] = *(const bh8*)(wqh + (size_t)((i >> 1) * 192 + (i & 1) * 16) * 192);
    #pragma unroll
    for (int jv = 0; jv < 2; ++jv)
        wv[jv] = *(const bh8*)(wqh + (size_t)(384 + jv * 16) * 192);
    __syncthreads();
    f4 aqk[4][4] = {}, av[4][2] = {};
    #pragma unroll
    for (int ks = 0; ks < 6; ++ks) {
        bh8 nqk[4], nv[2];
        if (ks < 5) {
            #pragma unroll
            for (int i = 0; i < 4; ++i)
                nqk[i] = *(const bh8*)(wqh + (size_t)((i >> 1) * 192 + (i & 1) * 16) * 192 + (ks + 1) * 32);
            #pragma unroll
            for (int jv = 0; jv < 2; ++jv)
                nv[jv] = *(const bh8*)(wqh + (size_t)(384 + jv * 16) * 192 + (ks + 1) * 32);
        }
        bh8 xf[4];
        #pragma unroll
        for (int mt = 0; mt < 4; ++mt)
            xf[mt] = *(const bh8*)&xsf[ks][mt * 16 + r][sxk];
        #pragma unroll
        for (int i = 0; i < 4; ++i)
            #pragma unroll
            for (int jn = 0; jn < 4; ++jn)
                aqk[i][jn] = MFMA(wqk[i], xf[jn], aqk[i][jn], 0, 0, 0);  // m=qkcol,n=token
        #pragma unroll
        for (int mt = 0; mt < 4; ++mt)
            #pragma unroll
            for (int jv = 0; jv < 2; ++jv)
                av[mt][jv] = MFMA(xf[mt], wv[jv], av[mt][jv], 0, 0, 0);  // m=token,n=vd
        if (ks < 5) {
            #pragma unroll
            for (int i = 0; i < 4; ++i) wqk[i] = nqk[i];
            wv[0] = nv[0]; wv[1] = nv[1];
        }
    }
    __syncthreads();   // xsf dead for ALL waves; vt overlay is now safe
    bf16* qkh = &qk[h][0][0][0];           // Q plane [0..2048), K plane [2048..4096)
    #pragma unroll
    for (int i = 0; i < 4; ++i) {
        const int t = i >> 1;
        const f4 bz = *(const f4*)&qkvb[t * 192 + h * 32 + (i & 1) * 16 + q * 4];
        const float sc = (i < 2) ? 0.17677669529663689f : 1.0f;  // scale Q only
        #pragma unroll
        for (int jn = 0; jn < 4; ++jn) {
            const int tok = jn * 16 + r;
            bh4 w;
            #pragma unroll
            for (int rr = 0; rr < 4; ++rr)
                w[rr] = f2bs((aqk[i][jn][rr] + bz[rr]) * sc);
            const int g = (((i & 1) * 4 + q) ^ ((tok & 3) << 1));
            *(bh4*)&qkh[(t * 64 + tok) * 32 + g * 4] = w;
        }
    }
    bf16* vth = &xsf[0][0][0] + h * 2048;  // vt overlay [32 d][64 tok] per head
    #pragma unroll
    for (int jv = 0; jv < 2; ++jv) {
        const float bv = qkvb[384 + h * 32 + jv * 16 + r];
        const int d = jv * 16 + r;
        #pragma unroll
        for (int mt = 0; mt < 4; ++mt) {
            bh4 w;
            #pragma unroll
            for (int rr = 0; rr < 4; ++rr)
                w[rr] = f2bs(av[mt][jv][rr] + bv);
            const int g = ((mt * 4 + q) ^ ((r & 7) << 1));
            *(bh4*)&vth[d * 64 + g * 4] = w;
        }
    }
    f4 as[4][4] = {};
    {
        const int sl = ((2 * q) ^ ((r & 3) << 1)) << 2;
        bh8 kf[4], qf[4];
        #pragma unroll
        for (int mt = 0; mt < 4; ++mt)
            kf[mt] = *(const bh8*)&qkh[(64 + mt * 16 + r) * 32 + sl];
        #pragma unroll
        for (int jn = 0; jn < 4; ++jn)
            qf[jn] = *(const bh8*)&qkh[(jn * 16 + r) * 32 + sl];
        #pragma unroll
        for (int mt = 0; mt < 4; ++mt)
            #pragma unroll
            for (int jn = 0; jn < 4; ++jn)
                as[mt][jn] = MFMA(kf[mt], qf[jn], as[mt][jn], 0, 0, 0);
    }
    const int rem = win & 255;
    const int cls = (((rem >> 4) == 15) ? 2 : 0) + (((rem & 15) == 15) ? 1 : 0);
    const float* bmh = bmp + ((size_t)(cls * 6 + h) << 12);
    #pragma unroll
    for (int jn = 0; jn < 4; ++jn) {
        const int qq = jn * 16 + r;
        #pragma unroll
        for (int mt = 0; mt < 4; ++mt) {
            const f4 b = *(const f4*)&bmh[qq * 64 + mt * 16 + q * 4];
            #pragma unroll
            for (int rr = 0; rr < 4; ++rr) as[mt][jn][rr] += b[rr];
        }
    }
    float inv4[4];
    #pragma unroll
    for (int jn = 0; jn < 4; ++jn) {
        float mx = -1e30f;
        #pragma unroll
        for (int mt = 0; mt < 4; ++mt)
            #pragma unroll
            for (int rr = 0; rr < 4; ++rr) mx = fmaxf(mx, as[mt][jn][rr]);
        mx = fmaxf(mx, __shfl_xor(mx, 16, 64));
        mx = fmaxf(mx, __shfl_xor(mx, 32, 64));
        float sm = 0.f;
        #pragma unroll
        for (int mt = 0; mt < 4; ++mt)
            #pragma unroll
            for (int rr = 0; rr < 4; ++rr) {
                float e = __expf(as[mt][jn][rr] - mx);
                as[mt][jn][rr] = e; sm += e;
            }
        sm += __shfl_xor(sm, 16, 64);
        sm += __shfl_xor(sm, 32, 64);
        inv4[jn] = __builtin_amdgcn_rcpf(sm);   // sm >= 1
    }
    #pragma unroll
    for (int jn = 0; jn < 4; ++jn) {
        const int qq = jn * 16 + r;
        #pragma unroll
        for (int mt = 0; mt < 4; ++mt) {
            bh4 w;
            #pragma unroll
            for (int rr = 0; rr < 4; ++rr) w[rr] = f2bs(as[mt][jn][rr] * inv4[jn]);
            const int g = ((mt * 4 + q) ^ ((r & 7) << 1));
            *(bh4*)&qkh[qq * 64 + g * 4] = w;
        }
    }
    f4 ao[4][2] = {};
    #pragma unroll
    for (int k2 = 0; k2 < 2; ++k2) {
        const int sl = ((k2 * 8 + 2 * q) ^ ((r & 7) << 1)) << 2;
        bh8 pf[4], vf[2];
        #pragma unroll
        for (int mt = 0; mt < 4; ++mt)
            pf[mt] = *(const bh8*)&qkh[(mt * 16 + r) * 64 + sl];
        #pragma unroll
        for (int jv = 0; jv < 2; ++jv)
            vf[jv] = *(const bh8*)&vth[(jv * 16 + r) * 64 + sl];
        #pragma unroll
        for (int mt = 0; mt < 4; ++mt)
            #pragma unroll
            for (int jv = 0; jv < 2; ++jv)
                ao[mt][jv] = MFMA(pf[mt], vf[jv], ao[mt][jv], 0, 0, 0);
    }
    #pragma unroll
    for (int mt = 0; mt < 4; ++mt)
        #pragma unroll
        for (int jv = 0; jv < 2; ++jv) {
            const int d = jv * 16 + r;
            #pragma unroll
            for (int rr = 0; rr < 4; ++rr) {
                const int qq = mt * 16 + q * 4 + rr;
                if (qq < 49)
                    attno[((size_t)win * 49 + qq) * 192 + h * 32 + d] =
                        __float2bfloat16(ao[mt][jv][rr]);
            }
        }
}

// ==== fused proj + residual + LN2 + MLP: 64 window-rows/block, 4 waves ====
// r15 champion: x1 stays in REGISTERS; LN2 -> dead As LDS; r6 mlp chunk loop;
// final out = x1 + fc2(gelu(fc1)) + b2 is a PURE WRITE.  LB(256,3), LDS 43520.
__global__ __launch_bounds__(256, 3)
void projmlp_kernel(const bf16* __restrict__ attno, const bf16* __restrict__ wp,
                    const float* __restrict__ projb, const float* __restrict__ xres,
                    const float* __restrict__ g2, const float* __restrict__ b2g,
                    const bf16* __restrict__ w1, const float* __restrict__ b1,
                    const bf16* __restrict__ w2, const float* __restrict__ b2,
                    float* __restrict__ out) {
    __shared__ __align__(16) bf16 As[6][64][32];   // attno tile -> later LN2 output
    __shared__ __align__(16) bf16 Hs[2][64][64];   // mlp H ping-pong
    __shared__ float rsum[64][4], rsq[64][4], mr[64][2];
    const int tid = threadIdx.x, wid = tid >> 6, lane = tid & 63;
    const int mbase = blockIdx.x * 64;
    const int r = lane & 15, q = lane >> 4, ko = q * 8;
    const int sxA = (q ^ ((r >> 1) & 3)) << 3;
    bf16* As0 = &As[0][0][0];
    // ---- stage attno tile (swizzled source, linear dest) ----
    #pragma unroll
    for (int it = 0; it < 6; ++it) {
        int l = it * 256 + wid * 64 + lane;
        int ks = l >> 8, rem2 = l & 255, row = rem2 >> 2;
        int g = (rem2 & 3) ^ ((row >> 1) & 3);
        gload16(attno + (size_t)(mbase + row) * 192 + ks * 32 + g * 8,
                As0 + (size_t)(it * 256 + wid * 64) * 8);
    }
    __syncthreads();
    // ---- proj GEMM: pacc[i][j] = rows(64) x cols(wave's 48), K=192 ----
    f4 pacc[4][3] = {};
    #pragma unroll
    for (int ks = 0; ks < 6; ++ks) {
        bh8 wpf[3];
        #pragma unroll
        for (int j = 0; j < 3; ++j)
            wpf[j] = *(const bh8*)&wp[(size_t)(wid * 48 + j * 16 + r) * 192 + ks * 32 + ko];
        #pragma unroll
        for (int i = 0; i < 4; ++i) {
            bh8 af = *(const bh8*)(As0 + ks * 2048 + (i * 16 + r) * 32 + sxA);
            #pragma unroll
            for (int j = 0; j < 3; ++j)
                pacc[i][j] = MFMA(af, wpf[j], pacc[i][j], 0, 0, 0);
        }
    }
    // ---- epilogue: + projb + x residual; per-row LN2 stats ----
    float pbv[3];
    #pragma unroll
    for (int j = 0; j < 3; ++j) pbv[j] = projb[wid * 48 + j * 16 + r];
    #pragma unroll
    for (int i = 0; i < 4; ++i) {
        int tok[4];
        float ps[4] = {}, pq2[4] = {};
        #pragma unroll
        for (int rr = 0; rr < 4; ++rr)
            tok[rr] = row2tok(mbase + i * 16 + q * 4 + rr);
        #pragma unroll
        for (int j = 0; j < 3; ++j) {
            const int col = wid * 48 + j * 16 + r;
            #pragma unroll
            for (int rr = 0; rr < 4; ++rr) {
                float v = pacc[i][j][rr] + pbv[j] + xres[(size_t)tok[rr] * 192 + col];
                pacc[i][j][rr] = v;
                ps[rr] += v; pq2[rr] += v * v;
            }
        }
        #pragma unroll
        for (int rr = 0; rr < 4; ++rr) {
            float s = ps[rr], qq = pq2[rr];
            #pragma unroll
            for (int o = 1; o < 16; o <<= 1) { s += __shfl_xor(s, o, 64); qq += __shfl_xor(qq, o, 64); }
            if (r == 0) {
                const int row = i * 16 + q * 4 + rr;
                rsum[row][wid] = s; rsq[row][wid] = qq;
            }
        }
    }
    __syncthreads();   // As reads done (proj GEMM) + rsum/rsq visible
    if (tid < 64) {
        float s = 0.f, qq = 0.f;
        #pragma unroll
        for (int w = 0; w < 4; ++w) { s += rsum[tid][w]; qq += rsq[tid][w]; }
        float m = s * (1.f / 192.f);
        float var = qq * (1.f / 192.f) - m * m;
        mr[tid][0] = m; mr[tid][1] = rsqrtf(var + 1e-5f);
    }
    __syncthreads();
    // ---- write hn = LN2(x1) into dead As (inverse-swizzled slots) ----
    #pragma unroll
    for (int j = 0; j < 3; ++j) {
        const int col = wid * 48 + j * 16 + r;
        const float gv = g2[col], bvv = b2g[col];
        const int ks2 = col >> 5, w32 = col & 31;
        #pragma unroll
        for (int i = 0; i < 4; ++i)
            #pragma unroll
            for (int rr = 0; rr < 4; ++rr) {
                const int row = i * 16 + q * 4 + rr;
                float hv = (pacc[i][j][rr] - mr[row][0]) * mr[row][1] * gv + bvv;
                const int slot8 = (w32 >> 3) ^ ((row >> 1) & 3);
                As0[ks2 * 2048 + row * 32 + slot8 * 8 + (w32 & 7)] = __float2bfloat16(hv);
            }
    }
    __syncthreads();
    // ---- mlp chunk loop (r6 structure + rcp-GELU) ----
    f4 acc2[4][3] = {};
    for (int c = 0; c < 12; ++c) {
        const int cb = c * 64;
        bh8 w1f[6];
        #pragma unroll
        for (int ks = 0; ks < 6; ++ks)
            w1f[ks] = *(const bh8*)&w1[(size_t)(cb + wid * 16 + r) * 192 + ks * 32 + ko];
        f4 acc1[4] = {};
        #pragma unroll
        for (int ks = 0; ks < 6; ++ks)
            #pragma unroll
            for (int i = 0; i < 4; ++i) {
                bh8 af = *(const bh8*)(As0 + ks * 2048 + (i * 16 + r) * 32 + sxA);
                acc1[i] = MFMA(af, w1f[ks], acc1[i], 0, 0, 0);
            }
        bh8 w2f[2][3];
        #pragma unroll
        for (int k2 = 0; k2 < 2; ++k2)
            #pragma unroll
            for (int j = 0; j < 3; ++j)
                w2f[k2][j] = *(const bh8*)&w2[(size_t)(wid * 48 + j * 16 + r) * 768 + cb + k2 * 32 + ko];
        const float b1v = b1[cb + wid * 16 + r];
        bf16 (*Hp)[64] = Hs[c & 1];
        #pragma unroll
        for (int i = 0; i < 4; ++i) {
            #pragma unroll
            for (int rr = 0; rr < 4; ++rr) {
                int row = i * 16 + q * 4 + rr;
                int col = wid * 16 + r;
                float v = acc1[i][rr] + b1v;
                float u = v * (1.5957691216f + 0.0713548162f * v * v);
                float en = __expf(-u);                        // overflow-safe sigmoid form
                float t = __builtin_amdgcn_rcpf(1.f + en);
                Hp[row][(((col >> 3) ^ (row & 7)) << 3) | (col & 7)] =
                    __float2bfloat16(v * t);                  // gelu_tanh
            }
        }
        __syncthreads();
        #pragma unroll
        for (int k2 = 0; k2 < 2; ++k2)
            #pragma unroll
            for (int i = 0; i < 4; ++i) {
                int row = i * 16 + r;
                bh8 af = *(const bh8*)(&Hp[row][0] + ((((k2 * 4 + q) ^ (row & 7)) & 7) << 3));
                #pragma unroll
                for (int j = 0; j < 3; ++j)
                    acc2[i][j] = MFMA(af, w2f[k2][j], acc2[i][j], 0, 0, 0);
            }
    }
    // ---- final: out = x1(regs) + mlp + b2 ; pure coalesced write, token scatter ----
    #pragma unroll
    for (int i = 0; i < 4; ++i) {
        int tok[4];
        #pragma unroll
        for (int rr = 0; rr < 4; ++rr)
            tok[rr] = row2tok(mbase + i * 16 + q * 4 + rr);
        #pragma unroll
        for (int j = 0; j < 3; ++j) {
            int ncol = wid * 48 + j * 16 + r;
            float bv = b2[ncol];
            #pragma unroll
            for (int rr = 0; rr < 4; ++rr)
                out[(size_t)tok[rr] * 192 + ncol] = pacc[i][j][rr] + acc2[i][j][rr] + bv;
        }
    }
}

extern "C" void kernel_launch(void* const* d_in, const int* in_sizes, int n_in,
                              void* d_out, int out_size, void* d_ws, size_t ws_size,
                              hipStream_t stream) {
    const float* x     = (const float*)d_in[0];
    const float* mask  = (const float*)d_in[1];
    const int*   rpi   = (const int*)d_in[2];
    const float* rpb   = (const float*)d_in[3];
    const float* n1g   = (const float*)d_in[4];
    const float* n1b   = (const float*)d_in[5];
    const float* qkvw  = (const float*)d_in[6];
    const float* qkvb  = (const float*)d_in[7];
    const float* projw = (const float*)d_in[8];
    const float* projb = (const float*)d_in[9];
    const float* n2g   = (const float*)d_in[10];
    const float* n2b   = (const float*)d_in[11];
    const float* fc1w  = (const float*)d_in[12];
    const float* fc1b  = (const float*)d_in[13];
    const float* fc2w  = (const float*)d_in[14];
    const float* fc2b  = (const float*)d_in[15];

    // ws layout (78.3 MB total):
    //  [0, 77,070,336)            attno bf16 (window order)
    //  [77,070,336, 77,463,552)   bmp fp32 (4x6x64x64)
    //  [77,463,552, 78,348,288)   bf16 weights contiguous (wq|wp|w1|w2)
    // xw (LN1 out) lives in d_out until projmlp's final stores overwrite it.
    char* ws = (char*)d_ws;
    bf16*  attno  = (bf16*)ws;
    float* bmp    = (float*)(ws + 77070336);
    bf16*  wq     = (bf16*)(ws + 77463552);
    bf16*  wp     = (bf16*)(ws + 77684736);
    bf16*  w1     = (bf16*)(ws + 77758464);
    bf16*  w2     = (bf16*)(ws + 78053376);
    bf16*  xw     = (bf16*)d_out;

    cvt_all<<<1728, 256, 0, stream>>>(qkvw, projw, fc1w, fc2w, wq);
    bmp_kernel<<<384, 256, 0, stream>>>(rpi, rpb, mask, bmp);

    ln_kernel<<<2048, 256, 0, stream>>>(x, n1g, n1b, xw);
    qkvattn_kernel<<<4096, 384, 0, stream>>>(xw, wq, qkvb, bmp, attno);
    projmlp_kernel<<<3136, 256, 0, stream>>>(attno, wp, projb, x, n2g, n2b,
                                             w1, fc1b, w2, fc2b, (float*)d_out);
}

// Round 21
// 592.878 us; speedup vs baseline: 1.1769x; 1.0057x over previous
//
#include <hip/hip_runtime.h>
#include <hip/hip_bf16.h>

typedef __hip_bfloat16 bf16;
typedef __attribute__((ext_vector_type(8))) short bh8;   // 8 bf16 (MFMA A/B frag)
typedef __attribute__((ext_vector_type(4))) short bh4;   // 4 bf16 (8B pack)
typedef __attribute__((ext_vector_type(4))) float f4;    // MFMA C/D frag

#define TOKENS 200704   // 16*112*112 = 4096 windows * 49
#define CDIM   192

__device__ __forceinline__ void gload16(const bf16* g, bf16* l) {
    __builtin_amdgcn_global_load_lds((const __attribute__((address_space(1))) void*)g,
                                     (__attribute__((address_space(3))) void*)l,
                                     16, 0, 0);
}
#define MFMA __builtin_amdgcn_mfma_f32_16x16x32_bf16

__device__ __forceinline__ short f2bs(float v) {
    bf16 h = __float2bfloat16(v); return *(short*)&h;
}

// window-row -> token index ((b,hs,ws) shifted back by +3)
__device__ __forceinline__ int row2tok(int row) {
    int win = row / 49, n = row - win * 49;
    int b = win >> 8, rem = win & 255;
    int hs = (rem >> 4) * 7 + n / 7;
    int wsx = (rem & 15) * 7 + n % 7;
    int hh = hs + 3; if (hh >= 112) hh -= 112;
    int ww = wsx + 3; if (ww >= 112) ww -= 112;
    return (b * 112 + hh) * 112 + ww;
}

// ---- fp32 -> bf16 conversion of all four weight matrices (contiguous dst) ----
__global__ void cvt_all(const float* __restrict__ a, const float* __restrict__ b,
                        const float* __restrict__ c, const float* __restrict__ d,
                        bf16* __restrict__ dst) {
    int i = blockIdx.x * 256 + threadIdx.x;
    if (i >= 442368) return;
    float v;
    if (i < 110592)       v = a[i];
    else if (i < 147456)  v = b[i - 110592];
    else if (i < 294912)  v = c[i - 147456];
    else                  v = d[i - 294912];
    dst[i] = __float2bfloat16(v);
}

// ---- padded bias+mask: bmp[cls][h][q:64][k:64]; k>=49 -> -1e30 (masks GEMM padding) ----
__global__ void bmp_kernel(const int* __restrict__ rpi, const float* __restrict__ tab,
                           const float* __restrict__ mask, float* __restrict__ bmp) {
    int idx = blockIdx.x * 256 + threadIdx.x;
    if (idx >= 98304) return;
    int cls = idx / 24576, rem = idx - cls * 24576;
    int h = rem >> 12, qk = rem & 4095;
    int qq = qk >> 6, kk = qk & 63;
    float v;
    if (kk >= 49) v = -1e30f;
    else if (qq >= 49) v = 0.f;
    else {
        int rep = ((cls & 2) ? 240 : 0) + ((cls & 1) ? 15 : 0);
        v = tab[rpi[qq * 49 + kk] * 6 + h] + mask[rep * 2401 + qq * 49 + kk];
    }
    bmp[idx] = v;
}

// ---- LayerNorm1 (fp32 in, bf16 out), shift(-3,-3) + window partition gather ----
__global__ __launch_bounds__(256)
void ln_kernel(const float* __restrict__ src, const float* __restrict__ gw,
               const float* __restrict__ bw, bf16* __restrict__ dst) {
    const int lane = threadIdx.x & 63;
    const int gwv  = (blockIdx.x * 256 + threadIdx.x) >> 6;
    const int nwv  = (gridDim.x * 256) >> 6;
    const float g0 = gw[lane], g1 = gw[lane + 64], g2 = gw[lane + 128];
    const float b0 = bw[lane], b1 = bw[lane + 64], b2 = bw[lane + 128];
    for (int row = gwv; row < TOKENS; row += nwv) {
        const float* p = src + (size_t)row2tok(row) * CDIM;
        float v0 = p[lane], v1 = p[lane + 64], v2 = p[lane + 128];
        float s = v0 + v1 + v2;
        float q = v0 * v0 + v1 * v1 + v2 * v2;
        #pragma unroll
        for (int o = 32; o; o >>= 1) { s += __shfl_xor(s, o, 64); q += __shfl_xor(q, o, 64); }
        float mean = s * (1.f / 192.f);
        float var  = q * (1.f / 192.f) - mean * mean;
        float rstd = rsqrtf(var + 1e-5f);
        bf16* d = dst + (size_t)row * CDIM;
        d[lane]       = __float2bfloat16((v0 - mean) * rstd * g0 + b0);
        d[lane + 64]  = __float2bfloat16((v1 - mean) * rstd * g1 + b1);
        d[lane + 128] = __float2bfloat16((v2 - mean) * rstd * g2 + b2);
    }
}

// ==== fused qkv-GEMM + MFMA attention (r13): 1 window/block, 6 waves (wave=head) ====
__global__ __launch_bounds__(384, 2)
void qkvattn_kernel(const bf16* __restrict__ xw, const bf16* __restrict__ wq,
                    const float* __restrict__ qkvb, const float* __restrict__ bmp,
                    bf16* __restrict__ attno) {
    __shared__ __align__(16) bf16 xsf[6][64][32];       // 24 KiB x-tile; later vt[6][32][64]
    __shared__ __align__(16) bf16 qk[6][2][64][32];     // 48 KiB Q,K; reused as P[h][64][64]
    const int tid = threadIdx.x, h = tid >> 6, lane = tid & 63;
    const int r = lane & 15, q = lane >> 4;
    const int win = blockIdx.x;
    const int sxk = (q ^ ((r >> 1) & 3)) << 3;

    #pragma unroll
    for (int it = 0; it < 4; ++it) {
        int l = it * 384 + tid;
        int ks = l >> 8, rem = l & 255, tok = rem >> 2;
        int kg = (rem & 3) ^ ((tok >> 1) & 3);
        int srow = win * 49 + tok; if (srow > 200703) srow = 200703;
        gload16(xw + (size_t)srow * 192 + ks * 32 + kg * 8,
                &xsf[0][0][0] + (size_t)l * 8);
    }
    const bf16* wqh = wq + (size_t)(h * 32 + r) * 192 + q * 8;
    bh8 wqk[4], wv[2];
    #pragma unroll
    for (int i = 0; i < 4; ++i)
        wqk[i] = *(const bh8*)(wqh + (size_t)((i >> 1) * 192 + (i & 1) * 16) * 192);
    #pragma unroll
    for (int jv = 0; jv < 2; ++jv)
        wv[jv] = *(const bh8*)(wqh + (size_t)(384 + jv * 16) * 192);
    __syncthreads();
    f4 aqk[4][4] = {}, av[4][2] = {};
    #pragma unroll
    for (int ks = 0; ks < 6; ++ks) {
        bh8 nqk[4], nv[2];
        if (ks < 5) {
            #pragma unroll
            for (int i = 0; i < 4; ++i)
                nqk[i] = *(const bh8*)(wqh + (size_t)((i >> 1) * 192 + (i & 1) * 16) * 192 + (ks + 1) * 32);
            #pragma unroll
            for (int jv = 0; jv < 2; ++jv)
                nv[jv] = *(const bh8*)(wqh + (size_t)(384 + jv * 16) * 192 + (ks + 1) * 32);
        }
        bh8 xf[4];
        #pragma unroll
        for (int mt = 0; mt < 4; ++mt)
            xf[mt] = *(const bh8*)&xsf[ks][mt * 16 + r][sxk];
        #pragma unroll
        for (int i = 0; i < 4; ++i)
            #pragma unroll
            for (int jn = 0; jn < 4; ++jn)
                aqk[i][jn] = MFMA(wqk[i], xf[jn], aqk[i][jn], 0, 0, 0);  // m=qkcol,n=token
        #pragma unroll
        for (int mt = 0; mt < 4; ++mt)
            #pragma unroll
            for (int jv = 0; jv < 2; ++jv)
                av[mt][jv] = MFMA(xf[mt], wv[jv], av[mt][jv], 0, 0, 0);  // m=token,n=vd
        if (ks < 5) {
            #pragma unroll
            for (int i = 0; i < 4; ++i) wqk[i] = nqk[i];
            wv[0] = nv[0]; wv[1] = nv[1];
        }
    }
    __syncthreads();   // xsf dead for ALL waves; vt overlay is now safe
    bf16* qkh = &qk[h][0][0][0];           // Q plane [0..2048), K plane [2048..4096)
    #pragma unroll
    for (int i = 0; i < 4; ++i) {
        const int t = i >> 1;
        const f4 bz = *(const f4*)&qkvb[t * 192 + h * 32 + (i & 1) * 16 + q * 4];
        const float sc = (i < 2) ? 0.17677669529663689f : 1.0f;  // scale Q only
        #pragma unroll
        for (int jn = 0; jn < 4; ++jn) {
            const int tok = jn * 16 + r;
            bh4 w;
            #pragma unroll
            for (int rr = 0; rr < 4; ++rr)
                w[rr] = f2bs((aqk[i][jn][rr] + bz[rr]) * sc);
            const int g = (((i & 1) * 4 + q) ^ ((tok & 3) << 1));
            *(bh4*)&qkh[(t * 64 + tok) * 32 + g * 4] = w;
        }
    }
    bf16* vth = &xsf[0][0][0] + h * 2048;  // vt overlay [32 d][64 tok] per head
    #pragma unroll
    for (int jv = 0; jv < 2; ++jv) {
        const float bv = qkvb[384 + h * 32 + jv * 16 + r];
        const int d = jv * 16 + r;
        #pragma unroll
        for (int mt = 0; mt < 4; ++mt) {
            bh4 w;
            #pragma unroll
            for (int rr = 0; rr < 4; ++rr)
                w[rr] = f2bs(av[mt][jv][rr] + bv);
            const int g = ((mt * 4 + q) ^ ((r & 7) << 1));
            *(bh4*)&vth[d * 64 + g * 4] = w;
        }
    }
    f4 as[4][4] = {};
    {
        const int sl = ((2 * q) ^ ((r & 3) << 1)) << 2;
        bh8 kf[4], qf[4];
        #pragma unroll
        for (int mt = 0; mt < 4; ++mt)
            kf[mt] = *(const bh8*)&qkh[(64 + mt * 16 + r) * 32 + sl];
        #pragma unroll
        for (int jn = 0; jn < 4; ++jn)
            qf[jn] = *(const bh8*)&qkh[(jn * 16 + r) * 32 + sl];
        #pragma unroll
        for (int mt = 0; mt < 4; ++mt)
            #pragma unroll
            for (int jn = 0; jn < 4; ++jn)
                as[mt][jn] = MFMA(kf[mt], qf[jn], as[mt][jn], 0, 0, 0);
    }
    const int rem = win & 255;
    const int cls = (((rem >> 4) == 15) ? 2 : 0) + (((rem & 15) == 15) ? 1 : 0);
    const float* bmh = bmp + ((size_t)(cls * 6 + h) << 12);
    #pragma unroll
    for (int jn = 0; jn < 4; ++jn) {
        const int qq = jn * 16 + r;
        #pragma unroll
        for (int mt = 0; mt < 4; ++mt) {
            const f4 b = *(const f4*)&bmh[qq * 64 + mt * 16 + q * 4];
            #pragma unroll
            for (int rr = 0; rr < 4; ++rr) as[mt][jn][rr] += b[rr];
        }
    }
    float inv4[4];
    #pragma unroll
    for (int jn = 0; jn < 4; ++jn) {
        float mx = -1e30f;
        #pragma unroll
        for (int mt = 0; mt < 4; ++mt)
            #pragma unroll
            for (int rr = 0; rr < 4; ++rr) mx = fmaxf(mx, as[mt][jn][rr]);
        mx = fmaxf(mx, __shfl_xor(mx, 16, 64));
        mx = fmaxf(mx, __shfl_xor(mx, 32, 64));
        float sm = 0.f;
        #pragma unroll
        for (int mt = 0; mt < 4; ++mt)
            #pragma unroll
            for (int rr = 0; rr < 4; ++rr) {
                float e = __expf(as[mt][jn][rr] - mx);
                as[mt][jn][rr] = e; sm += e;
            }
        sm += __shfl_xor(sm, 16, 64);
        sm += __shfl_xor(sm, 32, 64);
        inv4[jn] = __builtin_amdgcn_rcpf(sm);   // sm >= 1
    }
    #pragma unroll
    for (int jn = 0; jn < 4; ++jn) {
        const int qq = jn * 16 + r;
        #pragma unroll
        for (int mt = 0; mt < 4; ++mt) {
            bh4 w;
            #pragma unroll
            for (int rr = 0; rr < 4; ++rr) w[rr] = f2bs(as[mt][jn][rr] * inv4[jn]);
            const int g = ((mt * 4 + q) ^ ((r & 7) << 1));
            *(bh4*)&qkh[qq * 64 + g * 4] = w;
        }
    }
    f4 ao[4][2] = {};
    #pragma unroll
    for (int k2 = 0; k2 < 2; ++k2) {
        const int sl = ((k2 * 8 + 2 * q) ^ ((r & 7) << 1)) << 2;
        bh8 pf[4], vf[2];
        #pragma unroll
        for (int mt = 0; mt < 4; ++mt)
            pf[mt] = *(const bh8*)&qkh[(mt * 16 + r) * 64 + sl];
        #pragma unroll
        for (int jv = 0; jv < 2; ++jv)
            vf[jv] = *(const bh8*)&vth[(jv * 16 + r) * 64 + sl];
        #pragma unroll
        for (int mt = 0; mt < 4; ++mt)
            #pragma unroll
            for (int jv = 0; jv < 2; ++jv)
                ao[mt][jv] = MFMA(pf[mt], vf[jv], ao[mt][jv], 0, 0, 0);
    }
    #pragma unroll
    for (int mt = 0; mt < 4; ++mt)
        #pragma unroll
        for (int jv = 0; jv < 2; ++jv) {
            const int d = jv * 16 + r;
            #pragma unroll
            for (int rr = 0; rr < 4; ++rr) {
                const int qq = mt * 16 + q * 4 + rr;
                if (qq < 49)
                    attno[((size_t)win * 49 + qq) * 192 + h * 32 + d] =
                        __float2bfloat16(ao[mt][jv][rr]);
            }
        }
}

// ==== fused proj + residual + LN2 + MLP: 64 window-rows/block, 4 waves ====
// r15 champion + xres register prefetch: the 48 scattered residual loads are
// issued BEFORE the first barrier (latency hides under staging drain + proj
// GEMM).  LDS 43520 -> 3 blocks/CU is the occupancy cap, so VGPR may grow to
// ~170 without losing waves (84 + 48 xr + 16 tokm ~ 148).
__global__ __launch_bounds__(256, 3)
void projmlp_kernel(const bf16* __restrict__ attno, const bf16* __restrict__ wp,
                    const float* __restrict__ projb, const float* __restrict__ xres,
                    const float* __restrict__ g2, const float* __restrict__ b2g,
                    const bf16* __restrict__ w1, const float* __restrict__ b1,
                    const bf16* __restrict__ w2, const float* __restrict__ b2,
                    float* __restrict__ out) {
    __shared__ __align__(16) bf16 As[6][64][32];   // attno tile -> later LN2 output
    __shared__ __align__(16) bf16 Hs[2][64][64];   // mlp H ping-pong
    __shared__ float rsum[64][4], rsq[64][4], mr[64][2];
    const int tid = threadIdx.x, wid = tid >> 6, lane = tid & 63;
    const int mbase = blockIdx.x * 64;
    const int r = lane & 15, q = lane >> 4, ko = q * 8;
    const int sxA = (q ^ ((r >> 1) & 3)) << 3;
    bf16* As0 = &As[0][0][0];
    // ---- stage attno tile (swizzled source, linear dest) ----
    #pragma unroll
    for (int it = 0; it < 6; ++it) {
        int l = it * 256 + wid * 64 + lane;
        int ks = l >> 8, rem2 = l & 255, row = rem2 >> 2;
        int g = (rem2 & 3) ^ ((row >> 1) & 3);
        gload16(attno + (size_t)(mbase + row) * 192 + ks * 32 + g * 8,
                As0 + (size_t)(it * 256 + wid * 64) * 8);
    }
    // ---- EARLY: token indices + xres register prefetch (hides under GEMM) ----
    int tokm[4][4];
    #pragma unroll
    for (int i = 0; i < 4; ++i)
        #pragma unroll
        for (int rr = 0; rr < 4; ++rr)
            tokm[i][rr] = row2tok(mbase + i * 16 + q * 4 + rr);
    float xr[4][3][4];
    #pragma unroll
    for (int i = 0; i < 4; ++i)
        #pragma unroll
        for (int j = 0; j < 3; ++j) {
            const int col = wid * 48 + j * 16 + r;
            #pragma unroll
            for (int rr = 0; rr < 4; ++rr)
                xr[i][j][rr] = xres[(size_t)tokm[i][rr] * 192 + col];
        }
    __syncthreads();
    // ---- proj GEMM: pacc[i][j] = rows(64) x cols(wave's 48), K=192 ----
    f4 pacc[4][3] = {};
    #pragma unroll
    for (int ks = 0; ks < 6; ++ks) {
        bh8 wpf[3];
        #pragma unroll
        for (int j = 0; j < 3; ++j)
            wpf[j] = *(const bh8*)&wp[(size_t)(wid * 48 + j * 16 + r) * 192 + ks * 32 + ko];
        #pragma unroll
        for (int i = 0; i < 4; ++i) {
            bh8 af = *(const bh8*)(As0 + ks * 2048 + (i * 16 + r) * 32 + sxA);
            #pragma unroll
            for (int j = 0; j < 3; ++j)
                pacc[i][j] = MFMA(af, wpf[j], pacc[i][j], 0, 0, 0);
        }
    }
    // ---- epilogue: + projb + prefetched x residual; per-row LN2 stats ----
    float pbv[3];
    #pragma unroll
    for (int j = 0; j < 3; ++j) pbv[j] = projb[wid * 48 + j * 16 + r];
    #pragma unroll
    for (int i = 0; i < 4; ++i) {
        float ps[4] = {}, pq2[4] = {};
        #pragma unroll
        for (int j = 0; j < 3; ++j) {
            #pragma unroll
            for (int rr = 0; rr < 4; ++rr) {
                float v = pacc[i][j][rr] + pbv[j] + xr[i][j][rr];
                pacc[i][j][rr] = v;
                ps[rr] += v; pq2[rr] += v * v;
            }
        }
        #pragma unroll
        for (int rr = 0; rr < 4; ++rr) {
            float s = ps[rr], qq = pq2[rr];
            #pragma unroll
            for (int o = 1; o < 16; o <<= 1) { s += __shfl_xor(s, o, 64); qq += __shfl_xor(qq, o, 64); }
            if (r == 0) {
                const int row = i * 16 + q * 4 + rr;
                rsum[row][wid] = s; rsq[row][wid] = qq;
            }
        }
    }
    __syncthreads();   // As reads done (proj GEMM) + rsum/rsq visible
    if (tid < 64) {
        float s = 0.f, qq = 0.f;
        #pragma unroll
        for (int w = 0; w < 4; ++w) { s += rsum[tid][w]; qq += rsq[tid][w]; }
        float m = s * (1.f / 192.f);
        float var = qq * (1.f / 192.f) - m * m;
        mr[tid][0] = m; mr[tid][1] = rsqrtf(var + 1e-5f);
    }
    __syncthreads();
    // ---- write hn = LN2(x1) into dead As (inverse-swizzled slots) ----
    #pragma unroll
    for (int j = 0; j < 3; ++j) {
        const int col = wid * 48 + j * 16 + r;
        const float gv = g2[col], bvv = b2g[col];
        const int ks2 = col >> 5, w32 = col & 31;
        #pragma unroll
        for (int i = 0; i < 4; ++i)
            #pragma unroll
            for (int rr = 0; rr < 4; ++rr) {
                const int row = i * 16 + q * 4 + rr;
                float hv = (pacc[i][j][rr] - mr[row][0]) * mr[row][1] * gv + bvv;
                const int slot8 = (w32 >> 3) ^ ((row >> 1) & 3);
                As0[ks2 * 2048 + row * 32 + slot8 * 8 + (w32 & 7)] = __float2bfloat16(hv);
            }
    }
    __syncthreads();
    // ---- mlp chunk loop (r6 structure + rcp-GELU) ----
    f4 acc2[4][3] = {};
    for (int c = 0; c < 12; ++c) {
        const int cb = c * 64;
        bh8 w1f[6];
        #pragma unroll
        for (int ks = 0; ks < 6; ++ks)
            w1f[ks] = *(const bh8*)&w1[(size_t)(cb + wid * 16 + r) * 192 + ks * 32 + ko];
        f4 acc1[4] = {};
        #pragma unroll
        for (int ks = 0; ks < 6; ++ks)
            #pragma unroll
            for (int i = 0; i < 4; ++i) {
                bh8 af = *(const bh8*)(As0 + ks * 2048 + (i * 16 + r) * 32 + sxA);
                acc1[i] = MFMA(af, w1f[ks], acc1[i], 0, 0, 0);
            }
        bh8 w2f[2][3];
        #pragma unroll
        for (int k2 = 0; k2 < 2; ++k2)
            #pragma unroll
            for (int j = 0; j < 3; ++j)
                w2f[k2][j] = *(const bh8*)&w2[(size_t)(wid * 48 + j * 16 + r) * 768 + cb + k2 * 32 + ko];
        const float b1v = b1[cb + wid * 16 + r];
        bf16 (*Hp)[64] = Hs[c & 1];
        #pragma unroll
        for (int i = 0; i < 4; ++i) {
            #pragma unroll
            for (int rr = 0; rr < 4; ++rr) {
                int row = i * 16 + q * 4 + rr;
                int col = wid * 16 + r;
                float v = acc1[i][rr] + b1v;
                float u = v * (1.5957691216f + 0.0713548162f * v * v);
                float en = __expf(-u);                        // overflow-safe sigmoid form
                float t = __builtin_amdgcn_rcpf(1.f + en);
                Hp[row][(((col >> 3) ^ (row & 7)) << 3) | (col & 7)] =
                    __float2bfloat16(v * t);                  // gelu_tanh
            }
        }
        __syncthreads();
        #pragma unroll
        for (int k2 = 0; k2 < 2; ++k2)
            #pragma unroll
            for (int i = 0; i < 4; ++i) {
                int row = i * 16 + r;
                bh8 af = *(const bh8*)(&Hp[row][0] + ((((k2 * 4 + q) ^ (row & 7)) & 7) << 3));
                #pragma unroll
                for (int j = 0; j < 3; ++j)
                    acc2[i][j] = MFMA(af, w2f[k2][j], acc2[i][j], 0, 0, 0);
            }
    }
    // ---- final: out = x1(regs) + mlp + b2 ; pure coalesced write, token scatter ----
    #pragma unroll
    for (int i = 0; i < 4; ++i) {
        #pragma unroll
        for (int j = 0; j < 3; ++j) {
            int ncol = wid * 48 + j * 16 + r;
            float bv = b2[ncol];
            #pragma unroll
            for (int rr = 0; rr < 4; ++rr)
                out[(size_t)tokm[i][rr] * 192 + ncol] = pacc[i][j][rr] + acc2[i][j][rr] + bv;
        }
    }
}

extern "C" void kernel_launch(void* const* d_in, const int* in_sizes, int n_in,
                              void* d_out, int out_size, void* d_ws, size_t ws_size,
                              hipStream_t stream) {
    const float* x     = (const float*)d_in[0];
    const float* mask  = (const float*)d_in[1];
    const int*   rpi   = (const int*)d_in[2];
    const float* rpb   = (const float*)d_in[3];
    const float* n1g   = (const float*)d_in[4];
    const float* n1b   = (const float*)d_in[5];
    const float* qkvw  = (const float*)d_in[6];
    const float* qkvb  = (const float*)d_in[7];
    const float* projw = (const float*)d_in[8];
    const float* projb = (const float*)d_in[9];
    const float* n2g   = (const float*)d_in[10];
    const float* n2b   = (const float*)d_in[11];
    const float* fc1w  = (const float*)d_in[12];
    const float* fc1b  = (const float*)d_in[13];
    const float* fc2w  = (const float*)d_in[14];
    const float* fc2b  = (const float*)d_in[15];

    // ws layout (78.3 MB total):
    //  [0, 77,070,336)            attno bf16 (window order)
    //  [77,070,336, 77,463,552)   bmp fp32 (4x6x64x64)
    //  [77,463,552, 78,348,288)   bf16 weights contiguous (wq|wp|w1|w2)
    // xw (LN1 out) lives in d_out until projmlp's final stores overwrite it.
    char* ws = (char*)d_ws;
    bf16*  attno  = (bf16*)ws;
    float* bmp    = (float*)(ws + 77070336);
    bf16*  wq     = (bf16*)(ws + 77463552);
    bf16*  wp     = (bf16*)(ws + 77684736);
    bf16*  w1     = (bf16*)(ws + 77758464);
    bf16*  w2     = (bf16*)(ws + 78053376);
    bf16*  xw     = (bf16*)d_out;

    cvt_all<<<1728, 256, 0, stream>>>(qkvw, projw, fc1w, fc2w, wq);
    bmp_kernel<<<384, 256, 0, stream>>>(rpi, rpb, mask, bmp);

    ln_kernel<<<2048, 256, 0, stream>>>(x, n1g, n1b, xw);
    qkvattn_kernel<<<4096, 384, 0, stream>>>(xw, wq, qkvb, bmp, attno);
    projmlp_kernel<<<3136, 256, 0, stream>>>(attno, wp, projb, x, n2g, n2b,
                                             w1, fc1b, w2, fc2b, (float*)d_out);
}